// Round 2
// baseline (102.157 us; speedup 1.0000x reference)
//
#include <hip/hip_runtime.h>

// HyperLayer: y[b, f0/c0] += v * w0 * (wf1*x[b,f1] + wc1*x[b,c1])
// B=16, N=262144, DIM=8192.
//
// R17: R16 (fused scatter + global fp32 atomic flush, no partials, no d_ws)
// was CORRECT on a fresh call (absmax 0.0156) but failed post-timing:
// hipMemsetAsync did not survive stream-capture into the timed graph, so y
// accumulated across replays. Fix: zero y with a tiny KERNEL (kernels always
// capture as graph nodes). Keep everything else:
//  - FUSE reduce into scatter: LDS fixed-point accumulators flushed straight
//    into y via unsafeAtomicAdd (global_atomic_add_f32, L2-resident 512KB).
//    Drops the 16MB partials round-trip + reduce launch of R15.
//  - SPLITS=32: 512 blocks = 2 blocks/CU (64KB LDS of 160KB), 32 waves/CU;
//    one block's point-loop overlaps the other's stage/flush phases.
//  - 8 points/thread, fully unrolled.

#define BATCH 16
#define NPTS 262144
#define DIM 8192
#define SPLITS 32
#define PTS_PER_BLOCK (NPTS / SPLITS)   // 8192
#define BLOCK 1024
#define ITERS (PTS_PER_BLOCK / BLOCK)   // 8 -> fully unrolled

#define FP_SCALE 4194304.0f             // 2^22
#define FP_INV   (1.0f / 4194304.0f)

// Zero y (B*DIM floats = 512KB) as a graph-capturable kernel node.
// 32768 threads x one float4 store.
__global__ __launch_bounds__(256) void zero_y_kernel(float* __restrict__ y)
{
    const int i = blockIdx.x * 256 + threadIdx.x;   // [0, B*DIM/4)
    ((float4*)y)[i] = make_float4(0.f, 0.f, 0.f, 0.f);
}

__global__ __launch_bounds__(BLOCK, 8) void hyper_scatter_fused_kernel(
    const float* __restrict__ x,    // [B, DIM]
    const float* __restrict__ ri,   // [B, N, 2]
    const float* __restrict__ rv,   // [B, N]
    float* __restrict__ y)          // [B, DIM], zeroed by zero_y_kernel
{
    __shared__ float        x_s[DIM];   // 32 KB staged x row (LDS gather)
    __shared__ unsigned int S_s[DIM];   // 32 KB fixed-point accumulators

    const int tid   = threadIdx.x;
    const int split = blockIdx.x;
    const int b     = blockIdx.y;

    const float4* x4 = (const float4*)(x + (size_t)b * DIM);
    float4* xs4 = (float4*)x_s;
    uint4*  ss4 = (uint4*)S_s;
    #pragma unroll
    for (int i = tid; i < DIM / 4; i += BLOCK) {
        xs4[i] = x4[i];                     // L2-hit after first split per b
        ss4[i] = make_uint4(0u, 0u, 0u, 0u);
    }
    __syncthreads();

    const size_t base = (size_t)b * NPTS + (size_t)split * PTS_PER_BLOCK;
    const float2* idx2 = (const float2*)ri + base;
    const float*  val  = rv + base;

    #pragma unroll
    for (int k = 0; k < ITERS; ++k) {
        const int i = tid + k * BLOCK;
        float2 r = idx2[i];
        float v  = val[i];

        // frac-based corner weights. Reference semantics: w = 1-|corner-real|
        // for floor and ceil independently; integral index -> floor==ceil,
        // both weights 1, both land on the same slot (double count).
        float f0 = floorf(r.x);
        float fr0 = r.x - f0;                 // in [0,1)
        float wf0 = 1.0f - fr0;
        bool  int0 = (fr0 == 0.0f);
        float wc0 = int0 ? 1.0f : fr0;
        int   i0f = (int)f0;
        int   i0c = i0f + (int0 ? 0 : 1);

        float f1 = floorf(r.y);
        float fr1 = r.y - f1;
        float wf1 = 1.0f - fr1;
        bool  int1 = (fr1 == 0.0f);
        float wc1 = int1 ? 1.0f : fr1;
        int   i1f = (int)f1;
        int   i1c = i1f + (int1 ? 0 : 1);

        // Scattered LDS gather (near-free).
        float xa = x_s[i1f];
        float xb = x_s[i1c];

        float vg = v * (wf1 * xa + wc1 * xb);
        // Fixed-point integer LDS atomics (per-bank full-rate; wraparound-
        // exact two's complement).
        int ia = __float2int_rn(wf0 * vg * FP_SCALE);
        int ib = __float2int_rn(wc0 * vg * FP_SCALE);
        atomicAdd(&S_s[i0f], (unsigned int)ia);
        atomicAdd(&S_s[i0c], (unsigned int)ib);
    }
    __syncthreads();

    // Decode fixed-point -> fp32 and flush straight into y with native
    // fp32 global atomics (split-K style). 32 adds/address, L2-resident.
    float* yrow = y + (size_t)b * DIM;
    #pragma unroll
    for (int i = tid; i < DIM; i += BLOCK) {
        unsafeAtomicAdd(&yrow[i], (float)(int)S_s[i] * FP_INV);
    }
}

extern "C" void kernel_launch(void* const* d_in, const int* in_sizes, int n_in,
                              void* d_out, int out_size, void* d_ws, size_t ws_size,
                              hipStream_t stream) {
    const float* x  = (const float*)d_in[0];
    const float* ri = (const float*)d_in[1];
    const float* rv = (const float*)d_in[2];
    float* y = (float*)d_out;

    // Zero y via kernel (graph-capture-safe: always a graph node, unlike
    // hipMemsetAsync which got dropped from the captured graph in R16).
    zero_y_kernel<<<BATCH * DIM / 4 / 256, 256, 0, stream>>>(y);

    dim3 grid(SPLITS, BATCH);
    hyper_scatter_fused_kernel<<<grid, BLOCK, 0, stream>>>(x, ri, rv, y);
}